// Round 1
// baseline (148.663 us; speedup 1.0000x reference)
//
#include <hip/hip_runtime.h>

// CrossAttention with a single global token: K and V rows are identical per
// batch, so softmax is exactly uniform and the output collapses to
//   out[b, n, :] = (g[b] @ Wv + bv) @ Wo + bo        (independent of x, n)
// i.e. one 512-float row per batch broadcast across N=4096 positions.

#define BATCH      8
#define NPTS       4096
#define LOCAL_DIM  512
#define GLOBAL_DIM 128
#define HIDDEN_DIM 256

// ---------------------------------------------------------------------------
// Kernel 1: per-batch row compute. 8 blocks x 256 threads. ~1.3 MFLOP total.
// rows[b, j] = bo[j] + sum_h (bv[h] + sum_d g[b,d]*Wv[d,h]) * Wo[h,j]
// ---------------------------------------------------------------------------
__global__ void cross_attn_rows(const float* __restrict__ g,
                                const float* __restrict__ Wv,
                                const float* __restrict__ bv,
                                const float* __restrict__ Wo,
                                const float* __restrict__ bo,
                                float* __restrict__ rows) {
    __shared__ float gsh[GLOBAL_DIM];
    __shared__ float Vsh[HIDDEN_DIM];

    const int b = blockIdx.x;
    const int t = threadIdx.x;   // 0..255

    if (t < GLOBAL_DIM) gsh[t] = g[b * GLOBAL_DIM + t];
    __syncthreads();

    // V[h] = bv[h] + g[b,:] . Wv[:,h]   (HIDDEN_DIM == blockDim.x == 256)
    {
        const int h = t;
        float acc = bv[h];
        #pragma unroll 8
        for (int d = 0; d < GLOBAL_DIM; ++d)
            acc += gsh[d] * Wv[d * HIDDEN_DIM + h];
        Vsh[h] = acc;
    }
    __syncthreads();

    // row[j] = bo[j] + V . Wo[:, j]   (each thread does j = t and t + 256)
    for (int j = t; j < LOCAL_DIM; j += 256) {
        float acc = bo[j];
        #pragma unroll 8
        for (int h = 0; h < HIDDEN_DIM; ++h)
            acc += Vsh[h] * Wo[h * LOCAL_DIM + j];
        rows[b * LOCAL_DIM + j] = acc;
    }
}

// ---------------------------------------------------------------------------
// Kernel 2: broadcast rows to the full output. Pure write-BW bound (64 MiB).
// Total float4 elements = B*N*LOCAL_DIM/4 = 4,194,304.
// Grid-stride with stride a multiple of (LOCAL_DIM/4)=128 so each thread's
// row element index j4 is FIXED across iterations (row load stays L1-hot).
// ---------------------------------------------------------------------------
__global__ void cross_attn_bcast(const float4* __restrict__ rows4,
                                 float4* __restrict__ out4) {
    const long long total  = (long long)BATCH * NPTS * (LOCAL_DIM / 4); // 2^22
    const long long stride = (long long)gridDim.x * blockDim.x;         // multiple of 128
    long long idx = (long long)blockIdx.x * blockDim.x + threadIdx.x;

    const int j4 = (int)(idx & (LOCAL_DIM / 4 - 1)); // fixed per thread

    for (long long t = idx; t < total; t += stride) {
        // per-batch element count = NPTS * LOCAL_DIM/4 = 4096*128 = 2^19
        const int b = (int)(t >> 19);
        out4[t] = rows4[b * (LOCAL_DIM / 4) + j4];
    }
}

// ---------------------------------------------------------------------------
extern "C" void kernel_launch(void* const* d_in, const int* in_sizes, int n_in,
                              void* d_out, int out_size, void* d_ws, size_t ws_size,
                              hipStream_t stream) {
    // setup_inputs order: 0:x 1:g 2:Wq 3:bq 4:Wk 5:bk 6:Wv 7:bv 8:Wo 9:bo
    const float* g  = (const float*)d_in[1];
    const float* Wv = (const float*)d_in[6];
    const float* bv = (const float*)d_in[7];
    const float* Wo = (const float*)d_in[8];
    const float* bo = (const float*)d_in[9];

    float* rows = (float*)d_ws;  // BATCH * LOCAL_DIM floats = 16 KiB scratch

    cross_attn_rows<<<BATCH, 256, 0, stream>>>(g, Wv, bv, Wo, bo, rows);

    // 4096 blocks x 256 threads = 2^20 threads (stride multiple of 128),
    // 4 float4 stores per thread.
    cross_attn_bcast<<<4096, 256, 0, stream>>>((const float4*)rows,
                                               (float4*)d_out);
}

// Round 2
// 126.136 us; speedup vs baseline: 1.1786x; 1.1786x over previous
//
#include <hip/hip_runtime.h>

// CrossAttention with a single global token: K and V rows are identical per
// batch, so softmax is exactly uniform and the output collapses to
//   out[b, n, :] = (g[b] @ Wv + bv) @ Wo + bo        (independent of x, n)
// i.e. one 512-float row per batch broadcast across N=4096 positions.
//
// R1 post-mortem: rows kernel at 8 blocks was latency-bound (42.7 us,
// hbm 62 GB/s, occupancy 0.3%). This version spreads it over 128 blocks.

#define BATCH      8
#define NPTS       4096
#define LOCAL_DIM  512
#define GLOBAL_DIM 128
#define HIDDEN_DIM 256

// ---------------------------------------------------------------------------
// Kernel 1: per-batch row compute, parallelism-first.
// Grid = 8 batches x 16 j-chunks = 128 blocks, 256 threads.
// Each block recomputes V[b] (redundant but L2-cheap: Wv is 128 KB and hot
// after the first block per XCD touches it), then computes a 32-wide slice
// of row[b] with an 8-way h-split across the 256 threads.
// ---------------------------------------------------------------------------
__global__ void cross_attn_rows(const float* __restrict__ g,
                                const float* __restrict__ Wv,
                                const float* __restrict__ bv,
                                const float* __restrict__ Wo,
                                const float* __restrict__ bo,
                                float* __restrict__ rows) {
    __shared__ float gsh[GLOBAL_DIM];
    __shared__ float Vsh[HIDDEN_DIM];
    __shared__ float partial[8][32];

    const int b  = blockIdx.x >> 4;   // 0..7
    const int jc = blockIdx.x & 15;   // 0..15, each covers 32 j's
    const int t  = threadIdx.x;       // 0..255

    if (t < GLOBAL_DIM) gsh[t] = g[b * GLOBAL_DIM + t];
    __syncthreads();

    // V[h] = bv[h] + g[b,:] . Wv[:,h]  -- thread t owns h = t, coalesced Wv.
    {
        float acc = bv[t];
        #pragma unroll 16
        for (int d = 0; d < GLOBAL_DIM; ++d)
            acc += gsh[d] * Wv[d * HIDDEN_DIM + t];
        Vsh[t] = acc;
    }
    __syncthreads();

    // row[j] = bo[j] + V . Wo[:, j] for j in [jc*32, jc*32+32).
    // Thread t: j = jc*32 + (t&31), h-range [(t>>5)*32, +32). 8 partials per j.
    {
        const int j  = jc * 32 + (t & 31);
        const int h0 = (t >> 5) * 32;
        float p = 0.f;
        #pragma unroll
        for (int hh = 0; hh < 32; ++hh) {
            const int h = h0 + hh;
            p += Vsh[h] * Wo[h * LOCAL_DIM + j];
        }
        partial[t >> 5][t & 31] = p;
    }
    __syncthreads();

    if (t < 32) {
        const int j = jc * 32 + t;
        float r = bo[j];
        #pragma unroll
        for (int q = 0; q < 8; ++q) r += partial[q][t];
        rows[b * LOCAL_DIM + j] = r;
    }
}

// ---------------------------------------------------------------------------
// Kernel 2: broadcast rows to the full output. Pure write-BW bound (64 MiB).
// Total float4 elements = B*N*LOCAL_DIM/4 = 4,194,304.
// Grid-stride with stride a multiple of (LOCAL_DIM/4)=128 so each thread's
// row element index j4 is FIXED across iterations (row load stays L1-hot).
// ---------------------------------------------------------------------------
__global__ void cross_attn_bcast(const float4* __restrict__ rows4,
                                 float4* __restrict__ out4) {
    const long long total  = (long long)BATCH * NPTS * (LOCAL_DIM / 4); // 2^22
    const long long stride = (long long)gridDim.x * blockDim.x;         // multiple of 128
    long long idx = (long long)blockIdx.x * blockDim.x + threadIdx.x;

    const int j4 = (int)(idx & (LOCAL_DIM / 4 - 1)); // fixed per thread

    for (long long t = idx; t < total; t += stride) {
        // per-batch element count = NPTS * LOCAL_DIM/4 = 4096*128 = 2^19
        const int b = (int)(t >> 19);
        out4[t] = rows4[b * (LOCAL_DIM / 4) + j4];
    }
}

// ---------------------------------------------------------------------------
extern "C" void kernel_launch(void* const* d_in, const int* in_sizes, int n_in,
                              void* d_out, int out_size, void* d_ws, size_t ws_size,
                              hipStream_t stream) {
    // setup_inputs order: 0:x 1:g 2:Wq 3:bq 4:Wk 5:bk 6:Wv 7:bv 8:Wo 9:bo
    const float* g  = (const float*)d_in[1];
    const float* Wv = (const float*)d_in[6];
    const float* bv = (const float*)d_in[7];
    const float* Wo = (const float*)d_in[8];
    const float* bo = (const float*)d_in[9];

    float* rows = (float*)d_ws;  // BATCH * LOCAL_DIM floats = 16 KiB scratch

    cross_attn_rows<<<BATCH * 16, 256, 0, stream>>>(g, Wv, bv, Wo, bo, rows);

    // 4096 blocks x 256 threads = 2^20 threads (stride multiple of 128),
    // 4 float4 stores per thread.
    cross_attn_bcast<<<4096, 256, 0, stream>>>((const float4*)rows,
                                               (float4*)d_out);
}